// Round 5
// baseline (778.979 us; speedup 1.0000x reference)
//
#include <hip/hip_runtime.h>
#include <hip/hip_bf16.h>
#include <cstdint>
#include <cstddef>

// ---------------- types ----------------
typedef _Float16 f16;
typedef _Float16 f16x4 __attribute__((ext_vector_type(4)));
typedef _Float16 f16x8 __attribute__((ext_vector_type(8)));
typedef float f32x4 __attribute__((ext_vector_type(4)));

#define GPTR(p) ((const __attribute__((address_space(1))) void*)(p))
#define LPTR(p) ((__attribute__((address_space(3))) void*)(p))

// Problem constants
#define T_TOK 8192
#define H_DIM 1024
#define I_DIM 512
#define N_EXP 16          // routed experts; expert 16 = shared (weight 1.0, all tokens)
#define N_ALL 17
#define TOPK 2
#define NSLOT (T_TOK * TOPK)          // 16384 routed slots
#define NSLOT_ALL (NSLOT + T_TOK)     // 24576 incl. shared

// ---------------- one prep kernel: all casts + splits + bias copies + count zeroing ------
// block ranges (each block = 1024 f32 via 256 thr x float4):
//   [0,8192)      x -> split (x_h, x_l)
//   [8192,8208)   gw -> split (gw_h, gw_l)
//   [8208,24592)  wgu  -> wguA[0:16]
//   [24592,25616) wsgu -> wguA[16]
//   [25616,33808) wd   -> wdA[0:16]
//   [33808,34320) wsd  -> wdA[16]
//   [34320,34336) bgu  -> biasA[0:16]   (f32 copy)
//   [34336]       bsgu -> biasA[16]     (f32 copy)
//   [34337]       zero counts
#define PREP_BLOCKS 34338
__global__ void prep_kernel(const float* __restrict__ x, const float* __restrict__ gw,
                            const float* __restrict__ wgu, const float* __restrict__ wsgu,
                            const float* __restrict__ wd, const float* __restrict__ wsd,
                            const float* __restrict__ bgu, const float* __restrict__ bsgu,
                            f16* __restrict__ x_h, f16* __restrict__ x_l,
                            f16* __restrict__ gw_h, f16* __restrict__ gw_l,
                            f16* __restrict__ wguA, f16* __restrict__ wdA,
                            float* __restrict__ biasA, int* __restrict__ counts) {
    const int bid = blockIdx.x, tid = threadIdx.x;
    if (bid < 8192) {
        int i = bid * 256 + tid;
        float4 v = ((const float4*)x)[i];
        float vv[4] = { v.x, v.y, v.z, v.w };
        f16x4 h, l;
#pragma unroll
        for (int r = 0; r < 4; r++) { h[r] = (f16)vv[r]; l[r] = (f16)(vv[r] - (float)h[r]); }
        *(f16x4*)(x_h + (size_t)i * 4) = h;
        *(f16x4*)(x_l + (size_t)i * 4) = l;
    } else if (bid < 8208) {
        int i = (bid - 8192) * 256 + tid;
        float4 v = ((const float4*)gw)[i];
        float vv[4] = { v.x, v.y, v.z, v.w };
        f16x4 h, l;
#pragma unroll
        for (int r = 0; r < 4; r++) { h[r] = (f16)vv[r]; l[r] = (f16)(vv[r] - (float)h[r]); }
        *(f16x4*)(gw_h + (size_t)i * 4) = h;
        *(f16x4*)(gw_l + (size_t)i * 4) = l;
    } else if (bid < 24592) {
        int i = (bid - 8208) * 256 + tid;
        float4 v = ((const float4*)wgu)[i];
        f16x4 o = { (f16)v.x, (f16)v.y, (f16)v.z, (f16)v.w };
        *(f16x4*)(wguA + (size_t)i * 4) = o;
    } else if (bid < 25616) {
        int i = (bid - 24592) * 256 + tid;
        float4 v = ((const float4*)wsgu)[i];
        f16x4 o = { (f16)v.x, (f16)v.y, (f16)v.z, (f16)v.w };
        *(f16x4*)(wguA + (size_t)16 * 1024 * 1024 + (size_t)i * 4) = o;
    } else if (bid < 33808) {
        int i = (bid - 25616) * 256 + tid;
        float4 v = ((const float4*)wd)[i];
        f16x4 o = { (f16)v.x, (f16)v.y, (f16)v.z, (f16)v.w };
        *(f16x4*)(wdA + (size_t)i * 4) = o;
    } else if (bid < 34320) {
        int i = (bid - 33808) * 256 + tid;
        float4 v = ((const float4*)wsd)[i];
        f16x4 o = { (f16)v.x, (f16)v.y, (f16)v.z, (f16)v.w };
        *(f16x4*)(wdA + (size_t)16 * 1024 * 512 + (size_t)i * 4) = o;
    } else if (bid < 34336) {
        int i = (bid - 34320) * 256 + tid;
        ((float4*)biasA)[i] = ((const float4*)bgu)[i];
    } else if (bid == 34336) {
        ((float4*)(biasA + 16384))[tid] = ((const float4*)bsgu)[tid];
    } else {
        if (tid < 16) counts[tid] = 0;
    }
}

// ---------------- router logits via compensated MFMA: L = x @ gw^T in ~f32 precision ----
// logits = xh.gh + xh.gl + xl.gh  (xl.gl term ~1e-7, dropped).
__global__ __launch_bounds__(256) void logits_kernel(
    const f16* __restrict__ Xh, const f16* __restrict__ Xl,
    const f16* __restrict__ Gh, const f16* __restrict__ Gl,
    float* __restrict__ L) {
    const int wave = threadIdx.x >> 6, lane = threadIdx.x & 63;
    const int m0 = blockIdx.x * 64 + wave * 16;
    const int qm = lane & 15, quad = lane >> 4;
    const size_t arow = (size_t)(m0 + qm) * H_DIM + quad * 8;
    const size_t brow = (size_t)qm * H_DIM + quad * 8;
    f32x4 acc = (f32x4){0.f, 0.f, 0.f, 0.f};
    const f16* ap;
    const f16* bp;
    ap = Xh + arow; bp = Gh + brow;
#pragma unroll 8
    for (int k0 = 0; k0 < H_DIM; k0 += 32) {
        acc = __builtin_amdgcn_mfma_f32_16x16x32_f16(*(const f16x8*)ap, *(const f16x8*)bp, acc, 0, 0, 0);
        ap += 32; bp += 32;
    }
    ap = Xh + arow; bp = Gl + brow;
#pragma unroll 8
    for (int k0 = 0; k0 < H_DIM; k0 += 32) {
        acc = __builtin_amdgcn_mfma_f32_16x16x32_f16(*(const f16x8*)ap, *(const f16x8*)bp, acc, 0, 0, 0);
        ap += 32; bp += 32;
    }
    ap = Xl + arow; bp = Gh + brow;
#pragma unroll 8
    for (int k0 = 0; k0 < H_DIM; k0 += 32) {
        acc = __builtin_amdgcn_mfma_f32_16x16x32_f16(*(const f16x8*)ap, *(const f16x8*)bp, acc, 0, 0, 0);
        ap += 32; bp += 32;
    }
#pragma unroll
    for (int r = 0; r < 4; r++)
        L[(size_t)(m0 + quad * 4 + r) * N_EXP + qm] = acc[r];
}

// ---------------- top-2 + renorm weight + LDS histogram ----------------
__global__ void topk_kernel(const float* __restrict__ L, int* __restrict__ sel,
                            float* __restrict__ rw, int* __restrict__ counts) {
    __shared__ int lc[N_EXP];
    const int tid = threadIdx.x;
    if (tid < N_EXP) lc[tid] = 0;
    __syncthreads();
    const int t = blockIdx.x * 256 + tid;
    float lg[16];
    const float4* lp = (const float4*)(L + (size_t)t * N_EXP);
#pragma unroll
    for (int q = 0; q < 4; q++) {
        float4 v = lp[q];
        lg[q * 4 + 0] = v.x; lg[q * 4 + 1] = v.y; lg[q * 4 + 2] = v.z; lg[q * 4 + 3] = v.w;
    }
    float best = -1e30f, sec = -1e30f; int bi = 0, si = 0;
#pragma unroll
    for (int j = 0; j < 16; j++) {
        float lj = lg[j];
        if (lj > best) { sec = best; si = bi; best = lj; bi = j; }
        else if (lj > sec) { sec = lj; si = j; }
    }
    float w1 = 1.f / (1.f + __expf(sec - best));
    sel[t * 2] = bi; sel[t * 2 + 1] = si;
    rw[t * 2] = w1;  rw[t * 2 + 1] = 1.f - w1;
    atomicAdd(&lc[bi], 1);
    atomicAdd(&lc[si], 1);
    __syncthreads();
    if (tid < N_EXP) atomicAdd(&counts[tid], lc[tid]);
}

__global__ void prefix_kernel(const int* __restrict__ counts, int* __restrict__ offsets,
                              int* __restrict__ cursors) {
    if (threadIdx.x == 0) {
        int s = 0;
        for (int e = 0; e < N_EXP; e++) { offsets[e] = s; cursors[e] = s; s += counts[e]; }
        offsets[N_EXP] = s;                 // 16384
        offsets[N_EXP + 1] = s + T_TOK;     // 24576 (shared bucket)
    }
}

__global__ void scatter_kernel(const int* __restrict__ sel, const float* __restrict__ rw,
                               int* __restrict__ cursors, int* __restrict__ btok,
                               float* __restrict__ bw, int* __restrict__ pos) {
    int t = blockIdx.x * blockDim.x + threadIdx.x;
    if (t >= T_TOK) return;
#pragma unroll
    for (int k = 0; k < TOPK; k++) {
        int e = sel[t * 2 + k];
        int p = atomicAdd(&cursors[e], 1);
        btok[p] = t;
        bw[p] = rw[t * 2 + k];
        pos[t * 2 + k] = p;
    }
    btok[NSLOT + t] = t;     // shared bucket: identity
    bw[NSLOT + t] = 1.f;
}

// ---------------- fused gate_up + SiLU*up*bw: ACT[slot, 0:512] directly ----------------
// tile: 128 slots x 128 intermediate cols; gate rows (n0+c) and up rows (512+n0+c)
// both resident -> A-tile serves 256 output cols; GU round-trip eliminated.
__global__ __launch_bounds__(256) void gemm_gateup_act(
    const f16* __restrict__ X,        // [T,1024]
    const f16* __restrict__ W,        // [17,1024,1024]
    const float* __restrict__ bias,   // [17,1024]
    const float* __restrict__ bw,     // [24576]
    f16* __restrict__ ACT,            // [24576,512]
    const int* __restrict__ offsets,  // [18]
    const int* __restrict__ btok) {
    constexpr int K = H_DIM;
    const int e  = blockIdx.z;
    const int m0 = blockIdx.x * 128;
    const int n0 = blockIdx.y * 128;     // intermediate-col tile base: 0,128,256,384
    const int base = offsets[e];
    const int M = offsets[e + 1] - base;
    if (m0 >= M) return;

    const f16* Wb   = W + (size_t)e * 1024 * K;
    const float* bb = bias + (size_t)e * 1024;

    __shared__ f16 As[128 * 32];
    __shared__ f16 Bg[128 * 32];
    __shared__ f16 Bu[128 * 32];

    const int tid  = threadIdx.x;
    const int wave = tid >> 6;
    const int lane = tid & 63;
    const int srow = lane >> 2;          // 0..15
    const int scol = (lane & 3) * 8;     // 0,8,16,24

    int ar0 = m0 + wave * 32 + srow;
    int ar1 = ar0 + 16;
    int r0 = min(ar0, M - 1), r1 = min(ar1, M - 1);
    const f16* ap0 = X + (size_t)btok[base + r0] * K + scol;
    const f16* ap1 = X + (size_t)btok[base + r1] * K + scol;
    const f16* bg0 = Wb + (size_t)(n0 + wave * 32 + srow) * K + scol;
    const f16* bg1 = bg0 + (size_t)16 * K;
    const f16* bu0 = bg0 + (size_t)512 * K;
    const f16* bu1 = bu0 + (size_t)16 * K;
    f16* la0 = &As[(wave * 32) * 32];  f16* la1 = la0 + 16 * 32;
    f16* lg0 = &Bg[(wave * 32) * 32];  f16* lg1 = lg0 + 16 * 32;
    f16* lu0 = &Bu[(wave * 32) * 32];  f16* lu1 = lu0 + 16 * 32;

    const int wm = (wave >> 1) * 64;
    const int wn = (wave & 1) * 64;
    const int qm = lane & 15;
    const int quad = lane >> 4;

    f32x4 accg[4][4], accu[4][4];
#pragma unroll
    for (int i = 0; i < 4; i++)
#pragma unroll
        for (int j = 0; j < 4; j++) {
            accg[i][j] = (f32x4){0.f, 0.f, 0.f, 0.f};
            accu[i][j] = (f32x4){0.f, 0.f, 0.f, 0.f};
        }

    for (int k0 = 0; k0 < K; k0 += 32) {
        __builtin_amdgcn_global_load_lds(GPTR(ap0), LPTR(la0), 16, 0, 0);
        __builtin_amdgcn_global_load_lds(GPTR(ap1), LPTR(la1), 16, 0, 0);
        __builtin_amdgcn_global_load_lds(GPTR(bg0), LPTR(lg0), 16, 0, 0);
        __builtin_amdgcn_global_load_lds(GPTR(bg1), LPTR(lg1), 16, 0, 0);
        __builtin_amdgcn_global_load_lds(GPTR(bu0), LPTR(lu0), 16, 0, 0);
        __builtin_amdgcn_global_load_lds(GPTR(bu1), LPTR(lu1), 16, 0, 0);
        ap0 += 32; ap1 += 32; bg0 += 32; bg1 += 32; bu0 += 32; bu1 += 32;
        __syncthreads();
        f16x8 af[4], gf[4], uf[4];
#pragma unroll
        for (int i = 0; i < 4; i++) af[i] = *(const f16x8*)&As[(wm + i * 16 + qm) * 32 + quad * 8];
#pragma unroll
        for (int j = 0; j < 4; j++) {
            gf[j] = *(const f16x8*)&Bg[(wn + j * 16 + qm) * 32 + quad * 8];
            uf[j] = *(const f16x8*)&Bu[(wn + j * 16 + qm) * 32 + quad * 8];
        }
#pragma unroll
        for (int i = 0; i < 4; i++)
#pragma unroll
            for (int j = 0; j < 4; j++) {
                accg[i][j] = __builtin_amdgcn_mfma_f32_16x16x32_f16(af[i], gf[j], accg[i][j], 0, 0, 0);
                accu[i][j] = __builtin_amdgcn_mfma_f32_16x16x32_f16(af[i], uf[j], accu[i][j], 0, 0, 0);
            }
        __syncthreads();
    }

    // epilogue: act = silu(g+bg)*(u+bu)*bw  (C/D: col=lane&15, row=quad*4+reg)
#pragma unroll
    for (int i = 0; i < 4; i++) {
#pragma unroll
        for (int j = 0; j < 4; j++) {
            const int colg = n0 + wn + j * 16 + qm;
            const float bvg = bb[colg];
            const float bvu = bb[colg + 512];
#pragma unroll
            for (int r = 0; r < 4; r++) {
                const int lr = wm + i * 16 + quad * 4 + r;
                const int m = m0 + lr;
                if (m < M) {
                    float g = accg[i][j][r] + bvg;
                    float u = accu[i][j][r] + bvu;
                    float sl = g / (1.f + __expf(-g));
                    ACT[(size_t)(base + m) * 512 + colg] = (f16)(sl * u * bw[base + m]);
                }
            }
        }
    }
}

// ---------------- down GEMM 128x256: DOWN[slot, 0:1024] = ACT[slot] @ Wd_e^T ----------
__global__ __launch_bounds__(256) void gemm_down2(
    const f16* __restrict__ ACT,      // [24576,512]
    const f16* __restrict__ W,        // [17,1024,512]
    f16* __restrict__ DOWN,           // [24576,1024]
    const int* __restrict__ offsets) {
    constexpr int K = I_DIM;  // 512
    const int e  = blockIdx.z;
    const int m0 = blockIdx.x * 128;
    const int n0 = blockIdx.y * 256;     // output-col tile base: 0,256,512,768
    const int base = offsets[e];
    const int M = offsets[e + 1] - base;
    if (m0 >= M) return;

    const f16* Wb = W + (size_t)e * 1024 * K;

    __shared__ f16 As[128 * 32];
    __shared__ f16 B0[128 * 32];
    __shared__ f16 B1[128 * 32];

    const int tid  = threadIdx.x;
    const int wave = tid >> 6;
    const int lane = tid & 63;
    const int srow = lane >> 2;
    const int scol = (lane & 3) * 8;

    int ar0 = m0 + wave * 32 + srow;
    int ar1 = ar0 + 16;
    int r0 = min(ar0, M - 1), r1 = min(ar1, M - 1);
    const f16* ap0 = ACT + (size_t)(base + r0) * K + scol;
    const f16* ap1 = ACT + (size_t)(base + r1) * K + scol;
    const f16* b00 = Wb + (size_t)(n0 + wave * 32 + srow) * K + scol;
    const f16* b01 = b00 + (size_t)16 * K;
    const f16* b10 = b00 + (size_t)128 * K;
    const f16* b11 = b10 + (size_t)16 * K;
    f16* la0 = &As[(wave * 32) * 32];  f16* la1 = la0 + 16 * 32;
    f16* l00 = &B0[(wave * 32) * 32];  f16* l01 = l00 + 16 * 32;
    f16* l10 = &B1[(wave * 32) * 32];  f16* l11 = l10 + 16 * 32;

    const int wm = (wave >> 1) * 64;
    const int wn = (wave & 1) * 64;
    const int qm = lane & 15;
    const int quad = lane >> 4;

    f32x4 acc0[4][4], acc1[4][4];
#pragma unroll
    for (int i = 0; i < 4; i++)
#pragma unroll
        for (int j = 0; j < 4; j++) {
            acc0[i][j] = (f32x4){0.f, 0.f, 0.f, 0.f};
            acc1[i][j] = (f32x4){0.f, 0.f, 0.f, 0.f};
        }

    for (int k0 = 0; k0 < K; k0 += 32) {
        __builtin_amdgcn_global_load_lds(GPTR(ap0), LPTR(la0), 16, 0, 0);
        __builtin_amdgcn_global_load_lds(GPTR(ap1), LPTR(la1), 16, 0, 0);
        __builtin_amdgcn_global_load_lds(GPTR(b00), LPTR(l00), 16, 0, 0);
        __builtin_amdgcn_global_load_lds(GPTR(b01), LPTR(l01), 16, 0, 0);
        __builtin_amdgcn_global_load_lds(GPTR(b10), LPTR(l10), 16, 0, 0);
        __builtin_amdgcn_global_load_lds(GPTR(b11), LPTR(l11), 16, 0, 0);
        ap0 += 32; ap1 += 32; b00 += 32; b01 += 32; b10 += 32; b11 += 32;
        __syncthreads();
        f16x8 af[4], f0[4], f1[4];
#pragma unroll
        for (int i = 0; i < 4; i++) af[i] = *(const f16x8*)&As[(wm + i * 16 + qm) * 32 + quad * 8];
#pragma unroll
        for (int j = 0; j < 4; j++) {
            f0[j] = *(const f16x8*)&B0[(wn + j * 16 + qm) * 32 + quad * 8];
            f1[j] = *(const f16x8*)&B1[(wn + j * 16 + qm) * 32 + quad * 8];
        }
#pragma unroll
        for (int i = 0; i < 4; i++)
#pragma unroll
            for (int j = 0; j < 4; j++) {
                acc0[i][j] = __builtin_amdgcn_mfma_f32_16x16x32_f16(af[i], f0[j], acc0[i][j], 0, 0, 0);
                acc1[i][j] = __builtin_amdgcn_mfma_f32_16x16x32_f16(af[i], f1[j], acc1[i][j], 0, 0, 0);
            }
        __syncthreads();
    }

#pragma unroll
    for (int i = 0; i < 4; i++) {
#pragma unroll
        for (int j = 0; j < 4; j++) {
            const int col = n0 + wn + j * 16 + qm;
#pragma unroll
            for (int r = 0; r < 4; r++) {
                const int lr = wm + i * 16 + quad * 4 + r;
                const int m = m0 + lr;
                if (m < M) {
                    DOWN[(size_t)(base + m) * 1024 + col]       = (f16)acc0[i][j][r];
                    DOWN[(size_t)(base + m) * 1024 + col + 128] = (f16)acc1[i][j][r];
                }
            }
        }
    }
}

// ---------------- combine: out[t] = DOWN[16384+t] + DOWN[p1] + DOWN[p2] ----------------
__global__ void combine_kernel(const f16* __restrict__ DOWN, const int* __restrict__ pos,
                               float* __restrict__ OUT) {
    int idx = blockIdx.x * blockDim.x + threadIdx.x;
    int t = idx >> 8;             // 256 threads per token (1024 cols / 4)
    int c = (idx & 255) * 4;
    int p1 = pos[t * 2], p2 = pos[t * 2 + 1];
    f16x4 a = *(const f16x4*)(DOWN + (size_t)(NSLOT + t) * 1024 + c);
    f16x4 b = *(const f16x4*)(DOWN + (size_t)p1 * 1024 + c);
    f16x4 d = *(const f16x4*)(DOWN + (size_t)p2 * 1024 + c);
    float4 o;
    o.x = (float)a[0] + (float)b[0] + (float)d[0];
    o.y = (float)a[1] + (float)b[1] + (float)d[1];
    o.z = (float)a[2] + (float)b[2] + (float)d[2];
    o.w = (float)a[3] + (float)b[3] + (float)d[3];
    *(float4*)(OUT + (size_t)t * 1024 + c) = o;
}

// ---------------- host launch ----------------
extern "C" void kernel_launch(void* const* d_in, const int* in_sizes, int n_in,
                              void* d_out, int out_size, void* d_ws, size_t ws_size,
                              hipStream_t stream) {
    const float* x    = (const float*)d_in[0];   // [8192,1024]
    const float* gw   = (const float*)d_in[1];   // [16,1024]
    const float* wgu  = (const float*)d_in[2];   // [16,1024,1024]
    const float* bgu  = (const float*)d_in[3];   // [16,1024]
    const float* wd   = (const float*)d_in[4];   // [16,1024,512]
    const float* wsgu = (const float*)d_in[5];   // [1024,1024]
    const float* bsgu = (const float*)d_in[6];   // [1024]
    const float* wsd  = (const float*)d_in[7];   // [1024,512]
    float* out = (float*)d_out;

    char* ws = (char*)d_ws;
    size_t off = 0;
    auto take = [&](size_t b) { char* p = ws + off; off = (off + b + 255) & ~(size_t)255; return p; };
    f16* x_h    = (f16*)take((size_t)T_TOK * H_DIM * 2);
    f16* x_l    = (f16*)take((size_t)T_TOK * H_DIM * 2);
    f16* gw_h   = (f16*)take((size_t)N_EXP * H_DIM * 2);
    f16* gw_l   = (f16*)take((size_t)N_EXP * H_DIM * 2);
    f16* wguA   = (f16*)take((size_t)N_ALL * 1024 * H_DIM * 2);   // [17,1024,1024]
    f16* wdA    = (f16*)take((size_t)N_ALL * 1024 * I_DIM * 2);   // [17,1024,512]
    float* biasA = (float*)take((size_t)N_ALL * 1024 * 4);        // [17,1024]
    f16* act    = (f16*)take((size_t)NSLOT_ALL * I_DIM * 2);      // [24576,512]
    f16* down   = (f16*)take((size_t)NSLOT_ALL * 1024 * 2);       // [24576,1024]
    float* logits = (float*)take((size_t)T_TOK * N_EXP * 4);
    int*   sel    = (int*)take((size_t)NSLOT * 4);
    float* rw     = (float*)take((size_t)NSLOT * 4);
    int*   btok   = (int*)take((size_t)NSLOT_ALL * 4);
    float* bw     = (float*)take((size_t)NSLOT_ALL * 4);
    int*   pos    = (int*)take((size_t)NSLOT * 4);
    int*   counts = (int*)take(64);
    int*   offs   = (int*)take(128);
    int*   curs   = (int*)take(64);

    // 1) all casts/splits/copies/zeroing in one launch
    prep_kernel<<<PREP_BLOCKS, 256, 0, stream>>>(x, gw, wgu, wsgu, wd, wsd, bgu, bsgu,
                                                 x_h, x_l, gw_h, gw_l, wguA, wdA, biasA, counts);

    // 2) routing
    logits_kernel<<<T_TOK / 64, 256, 0, stream>>>(x_h, x_l, gw_h, gw_l, logits);
    topk_kernel<<<T_TOK / 256, 256, 0, stream>>>(logits, sel, rw, counts);
    prefix_kernel<<<1, 64, 0, stream>>>(counts, offs, curs);
    scatter_kernel<<<T_TOK / 256, 256, 0, stream>>>(sel, rw, curs, btok, bw, pos);

    // 3) fused gate_up + SiLU*up*bw -> ACT
    gemm_gateup_act<<<dim3(128, 4, N_ALL), 256, 0, stream>>>(x_h, wguA, biasA, bw, act, offs, btok);

    // 4) down GEMM (128x256 tile) -> DOWN
    gemm_down2<<<dim3(128, 4, N_ALL), 256, 0, stream>>>(act, wdA, down, offs);

    // 5) combine
    combine_kernel<<<T_TOK * 1024 / 4 / 256, 256, 0, stream>>>(down, pos, out);
}

// Round 6
// 534.581 us; speedup vs baseline: 1.4572x; 1.4572x over previous
//
#include <hip/hip_runtime.h>
#include <hip/hip_bf16.h>
#include <cstdint>
#include <cstddef>

// ---------------- types ----------------
typedef _Float16 f16;
typedef _Float16 f16x4 __attribute__((ext_vector_type(4)));
typedef _Float16 f16x8 __attribute__((ext_vector_type(8)));
typedef float f32x4 __attribute__((ext_vector_type(4)));

#define GPTR(p) ((const __attribute__((address_space(1))) void*)(p))
#define LPTR(p) ((__attribute__((address_space(3))) void*)(p))

// Problem constants
#define T_TOK 8192
#define H_DIM 1024
#define I_DIM 512
#define N_EXP 16          // routed experts; expert 16 = shared (weight 1.0, all tokens)
#define N_ALL 17
#define TOPK 2
#define NSLOT (T_TOK * TOPK)          // 16384 routed slots
#define NSLOT_ALL (NSLOT + T_TOK)     // 24576 incl. shared

// ---------------- one prep kernel: all casts + splits + bias copies + count zeroing ------
#define PREP_BLOCKS 34338
__global__ void prep_kernel(const float* __restrict__ x, const float* __restrict__ gw,
                            const float* __restrict__ wgu, const float* __restrict__ wsgu,
                            const float* __restrict__ wd, const float* __restrict__ wsd,
                            const float* __restrict__ bgu, const float* __restrict__ bsgu,
                            f16* __restrict__ x_h, f16* __restrict__ x_l,
                            f16* __restrict__ gw_h, f16* __restrict__ gw_l,
                            f16* __restrict__ wguA, f16* __restrict__ wdA,
                            float* __restrict__ biasA, int* __restrict__ counts) {
    const int bid = blockIdx.x, tid = threadIdx.x;
    if (bid < 8192) {
        int i = bid * 256 + tid;
        float4 v = ((const float4*)x)[i];
        float vv[4] = { v.x, v.y, v.z, v.w };
        f16x4 h, l;
#pragma unroll
        for (int r = 0; r < 4; r++) { h[r] = (f16)vv[r]; l[r] = (f16)(vv[r] - (float)h[r]); }
        *(f16x4*)(x_h + (size_t)i * 4) = h;
        *(f16x4*)(x_l + (size_t)i * 4) = l;
    } else if (bid < 8208) {
        int i = (bid - 8192) * 256 + tid;
        float4 v = ((const float4*)gw)[i];
        float vv[4] = { v.x, v.y, v.z, v.w };
        f16x4 h, l;
#pragma unroll
        for (int r = 0; r < 4; r++) { h[r] = (f16)vv[r]; l[r] = (f16)(vv[r] - (float)h[r]); }
        *(f16x4*)(gw_h + (size_t)i * 4) = h;
        *(f16x4*)(gw_l + (size_t)i * 4) = l;
    } else if (bid < 24592) {
        int i = (bid - 8208) * 256 + tid;
        float4 v = ((const float4*)wgu)[i];
        f16x4 o = { (f16)v.x, (f16)v.y, (f16)v.z, (f16)v.w };
        *(f16x4*)(wguA + (size_t)i * 4) = o;
    } else if (bid < 25616) {
        int i = (bid - 24592) * 256 + tid;
        float4 v = ((const float4*)wsgu)[i];
        f16x4 o = { (f16)v.x, (f16)v.y, (f16)v.z, (f16)v.w };
        *(f16x4*)(wguA + (size_t)16 * 1024 * 1024 + (size_t)i * 4) = o;
    } else if (bid < 33808) {
        int i = (bid - 25616) * 256 + tid;
        float4 v = ((const float4*)wd)[i];
        f16x4 o = { (f16)v.x, (f16)v.y, (f16)v.z, (f16)v.w };
        *(f16x4*)(wdA + (size_t)i * 4) = o;
    } else if (bid < 34320) {
        int i = (bid - 33808) * 256 + tid;
        float4 v = ((const float4*)wsd)[i];
        f16x4 o = { (f16)v.x, (f16)v.y, (f16)v.z, (f16)v.w };
        *(f16x4*)(wdA + (size_t)16 * 1024 * 512 + (size_t)i * 4) = o;
    } else if (bid < 34336) {
        int i = (bid - 34320) * 256 + tid;
        ((float4*)biasA)[i] = ((const float4*)bgu)[i];
    } else if (bid == 34336) {
        ((float4*)(biasA + 16384))[tid] = ((const float4*)bsgu)[tid];
    } else {
        if (tid < 16) counts[tid] = 0;
    }
}

// ---------------- router logits via compensated MFMA: L = x @ gw^T in ~f32 precision ----
__global__ __launch_bounds__(256) void logits_kernel(
    const f16* __restrict__ Xh, const f16* __restrict__ Xl,
    const f16* __restrict__ Gh, const f16* __restrict__ Gl,
    float* __restrict__ L) {
    const int wave = threadIdx.x >> 6, lane = threadIdx.x & 63;
    const int m0 = blockIdx.x * 64 + wave * 16;
    const int qm = lane & 15, quad = lane >> 4;
    const size_t arow = (size_t)(m0 + qm) * H_DIM + quad * 8;
    const size_t brow = (size_t)qm * H_DIM + quad * 8;
    f32x4 acc = (f32x4){0.f, 0.f, 0.f, 0.f};
    const f16* ap;
    const f16* bp;
    ap = Xh + arow; bp = Gh + brow;
#pragma unroll 8
    for (int k0 = 0; k0 < H_DIM; k0 += 32) {
        acc = __builtin_amdgcn_mfma_f32_16x16x32_f16(*(const f16x8*)ap, *(const f16x8*)bp, acc, 0, 0, 0);
        ap += 32; bp += 32;
    }
    ap = Xh + arow; bp = Gl + brow;
#pragma unroll 8
    for (int k0 = 0; k0 < H_DIM; k0 += 32) {
        acc = __builtin_amdgcn_mfma_f32_16x16x32_f16(*(const f16x8*)ap, *(const f16x8*)bp, acc, 0, 0, 0);
        ap += 32; bp += 32;
    }
    ap = Xl + arow; bp = Gh + brow;
#pragma unroll 8
    for (int k0 = 0; k0 < H_DIM; k0 += 32) {
        acc = __builtin_amdgcn_mfma_f32_16x16x32_f16(*(const f16x8*)ap, *(const f16x8*)bp, acc, 0, 0, 0);
        ap += 32; bp += 32;
    }
#pragma unroll
    for (int r = 0; r < 4; r++)
        L[(size_t)(m0 + quad * 4 + r) * N_EXP + qm] = acc[r];
}

// ---------------- top-2 + renorm weight + LDS histogram ----------------
__global__ void topk_kernel(const float* __restrict__ L, int* __restrict__ sel,
                            float* __restrict__ rw, int* __restrict__ counts) {
    __shared__ int lc[N_EXP];
    const int tid = threadIdx.x;
    if (tid < N_EXP) lc[tid] = 0;
    __syncthreads();
    const int t = blockIdx.x * 256 + tid;
    float lg[16];
    const float4* lp = (const float4*)(L + (size_t)t * N_EXP);
#pragma unroll
    for (int q = 0; q < 4; q++) {
        float4 v = lp[q];
        lg[q * 4 + 0] = v.x; lg[q * 4 + 1] = v.y; lg[q * 4 + 2] = v.z; lg[q * 4 + 3] = v.w;
    }
    float best = -1e30f, sec = -1e30f; int bi = 0, si = 0;
#pragma unroll
    for (int j = 0; j < 16; j++) {
        float lj = lg[j];
        if (lj > best) { sec = best; si = bi; best = lj; bi = j; }
        else if (lj > sec) { sec = lj; si = j; }
    }
    float w1 = 1.f / (1.f + __expf(sec - best));
    sel[t * 2] = bi; sel[t * 2 + 1] = si;
    rw[t * 2] = w1;  rw[t * 2 + 1] = 1.f - w1;
    atomicAdd(&lc[bi], 1);
    atomicAdd(&lc[si], 1);
    __syncthreads();
    if (tid < N_EXP) atomicAdd(&counts[tid], lc[tid]);
}

__global__ void prefix_kernel(const int* __restrict__ counts, int* __restrict__ offsets,
                              int* __restrict__ cursors) {
    if (threadIdx.x == 0) {
        int s = 0;
        for (int e = 0; e < N_EXP; e++) { offsets[e] = s; cursors[e] = s; s += counts[e]; }
        offsets[N_EXP] = s;                 // 16384
        offsets[N_EXP + 1] = s + T_TOK;     // 24576 (shared bucket)
    }
}

__global__ void scatter_kernel(const int* __restrict__ sel, const float* __restrict__ rw,
                               int* __restrict__ cursors, int* __restrict__ btok,
                               float* __restrict__ bw, int* __restrict__ pos) {
    int t = blockIdx.x * blockDim.x + threadIdx.x;
    if (t >= T_TOK) return;
#pragma unroll
    for (int k = 0; k < TOPK; k++) {
        int e = sel[t * 2 + k];
        int p = atomicAdd(&cursors[e], 1);
        btok[p] = t;
        bw[p] = rw[t * 2 + k];
        pos[t * 2 + k] = p;
    }
    btok[NSLOT + t] = t;     // shared bucket: identity
    bw[NSLOT + t] = 1.f;
}

// ---------------- fused gate_up + SiLU*up*bw, v2: 128 slots x 64 inter cols ----------------
// acc = accg[4][2]+accu[4][2] = 64 regs (vs 128 in v1 -> occupancy cliff).
// __launch_bounds__(256,4): force <=128 unified regs -> 4 waves/SIMD.
__global__ __launch_bounds__(256, 4) void gemm_gateup_act(
    const f16* __restrict__ X,        // [T,1024]
    const f16* __restrict__ W,        // [17,1024,1024]
    const float* __restrict__ bias,   // [17,1024]
    const float* __restrict__ bw,     // [24576]
    f16* __restrict__ ACT,            // [24576,512]
    const int* __restrict__ offsets,  // [18]
    const int* __restrict__ btok) {
    constexpr int K = H_DIM;
    const int e  = blockIdx.z;
    const int m0 = blockIdx.x * 128;
    const int n0 = blockIdx.y * 64;      // intermediate-col tile base: 0..448 step 64
    const int base = offsets[e];
    const int M = offsets[e + 1] - base;
    if (m0 >= M) return;

    const f16* Wb   = W + (size_t)e * 1024 * K;
    const float* bb = bias + (size_t)e * 1024;

    __shared__ f16 As[128 * 32];
    __shared__ f16 Bg[64 * 32];
    __shared__ f16 Bu[64 * 32];

    const int tid  = threadIdx.x;
    const int wave = tid >> 6;
    const int lane = tid & 63;
    const int srow = lane >> 2;          // 0..15
    const int scol = (lane & 3) * 8;     // 0,8,16,24

    // A staging: wave w fills rows [w*32, w*32+32)
    int ar0 = m0 + wave * 32 + srow;
    int ar1 = ar0 + 16;
    int r0 = min(ar0, M - 1), r1 = min(ar1, M - 1);
    const f16* ap0 = X + (size_t)btok[base + r0] * K + scol;
    const f16* ap1 = X + (size_t)btok[base + r1] * K + scol;
    // B staging: wave w fills rows [w*16, w*16+16) of Bg and Bu
    const int brow = n0 + wave * 16 + srow;
    const f16* bg0 = Wb + (size_t)brow * K + scol;
    const f16* bu0 = bg0 + (size_t)512 * K;
    f16* la0 = &As[(wave * 32) * 32];  f16* la1 = la0 + 16 * 32;
    f16* lg0 = &Bg[(wave * 16) * 32];
    f16* lu0 = &Bu[(wave * 16) * 32];

    const int wm = (wave >> 1) * 64;
    const int wn = (wave & 1) * 32;
    const int qm = lane & 15;
    const int quad = lane >> 4;

    f32x4 accg[4][2], accu[4][2];
#pragma unroll
    for (int i = 0; i < 4; i++)
#pragma unroll
        for (int j = 0; j < 2; j++) {
            accg[i][j] = (f32x4){0.f, 0.f, 0.f, 0.f};
            accu[i][j] = (f32x4){0.f, 0.f, 0.f, 0.f};
        }

    for (int k0 = 0; k0 < K; k0 += 32) {
        __builtin_amdgcn_global_load_lds(GPTR(ap0), LPTR(la0), 16, 0, 0);
        __builtin_amdgcn_global_load_lds(GPTR(ap1), LPTR(la1), 16, 0, 0);
        __builtin_amdgcn_global_load_lds(GPTR(bg0), LPTR(lg0), 16, 0, 0);
        __builtin_amdgcn_global_load_lds(GPTR(bu0), LPTR(lu0), 16, 0, 0);
        ap0 += 32; ap1 += 32; bg0 += 32; bu0 += 32;
        __syncthreads();
        f16x8 af[4], gf[2], uf[2];
#pragma unroll
        for (int i = 0; i < 4; i++) af[i] = *(const f16x8*)&As[(wm + i * 16 + qm) * 32 + quad * 8];
#pragma unroll
        for (int j = 0; j < 2; j++) {
            gf[j] = *(const f16x8*)&Bg[(wn + j * 16 + qm) * 32 + quad * 8];
            uf[j] = *(const f16x8*)&Bu[(wn + j * 16 + qm) * 32 + quad * 8];
        }
#pragma unroll
        for (int i = 0; i < 4; i++)
#pragma unroll
            for (int j = 0; j < 2; j++) {
                accg[i][j] = __builtin_amdgcn_mfma_f32_16x16x32_f16(af[i], gf[j], accg[i][j], 0, 0, 0);
                accu[i][j] = __builtin_amdgcn_mfma_f32_16x16x32_f16(af[i], uf[j], accu[i][j], 0, 0, 0);
            }
        __syncthreads();
    }

    // epilogue: act = silu(g+bg)*(u+bu)*bw  (C/D: col=lane&15, row=quad*4+reg)
#pragma unroll
    for (int i = 0; i < 4; i++) {
#pragma unroll
        for (int j = 0; j < 2; j++) {
            const int colg = n0 + wn + j * 16 + qm;
            const float bvg = bb[colg];
            const float bvu = bb[colg + 512];
#pragma unroll
            for (int r = 0; r < 4; r++) {
                const int lr = wm + i * 16 + quad * 4 + r;
                const int m = m0 + lr;
                if (m < M) {
                    float g = accg[i][j][r] + bvg;
                    float u = accu[i][j][r] + bvu;
                    float sl = g / (1.f + __expf(-g));
                    ACT[(size_t)(base + m) * 512 + colg] = (f16)(sl * u * bw[base + m]);
                }
            }
        }
    }
}

// ---------------- down GEMM 128x128 (round-4 known-good) + launch bound ----------------
__global__ __launch_bounds__(256, 4) void gemm_down(
    const f16* __restrict__ ACT,      // [24576,512]
    const f16* __restrict__ W,        // [17,1024,512]
    f16* __restrict__ DOWN,           // [24576,1024]
    const int* __restrict__ offsets) {
    constexpr int K = I_DIM;  // 512
    const int e  = blockIdx.z;
    const int m0 = blockIdx.x * 128;
    const int n0 = blockIdx.y * 128;
    const int base = offsets[e];
    const int M = offsets[e + 1] - base;
    if (m0 >= M) return;

    const f16* Wb = W + (size_t)e * 1024 * K;

    __shared__ f16 As[128 * 32];
    __shared__ f16 Bs[128 * 32];

    const int tid  = threadIdx.x;
    const int wave = tid >> 6;
    const int lane = tid & 63;
    const int srow = lane >> 2;
    const int scol = (lane & 3) * 8;

    int ar0 = m0 + wave * 32 + srow;
    int ar1 = ar0 + 16;
    int r0 = min(ar0, M - 1), r1 = min(ar1, M - 1);
    const f16* ap0 = ACT + (size_t)(base + r0) * K + scol;
    const f16* ap1 = ACT + (size_t)(base + r1) * K + scol;
    const f16* bp0 = Wb + (size_t)(n0 + wave * 32 + srow) * K + scol;
    const f16* bp1 = bp0 + (size_t)16 * K;
    f16* la0 = &As[(wave * 32) * 32];  f16* la1 = la0 + 16 * 32;
    f16* lb0 = &Bs[(wave * 32) * 32];  f16* lb1 = lb0 + 16 * 32;

    const int wm = (wave >> 1) * 64;
    const int wn = (wave & 1) * 64;
    const int qm = lane & 15;
    const int quad = lane >> 4;

    f32x4 acc[4][4];
#pragma unroll
    for (int i = 0; i < 4; i++)
#pragma unroll
        for (int j = 0; j < 4; j++) acc[i][j] = (f32x4){0.f, 0.f, 0.f, 0.f};

    for (int k0 = 0; k0 < K; k0 += 32) {
        __builtin_amdgcn_global_load_lds(GPTR(ap0), LPTR(la0), 16, 0, 0);
        __builtin_amdgcn_global_load_lds(GPTR(ap1), LPTR(la1), 16, 0, 0);
        __builtin_amdgcn_global_load_lds(GPTR(bp0), LPTR(lb0), 16, 0, 0);
        __builtin_amdgcn_global_load_lds(GPTR(bp1), LPTR(lb1), 16, 0, 0);
        ap0 += 32; ap1 += 32; bp0 += 32; bp1 += 32;
        __syncthreads();
        f16x8 af[4], bfr[4];
#pragma unroll
        for (int i = 0; i < 4; i++) af[i]  = *(const f16x8*)&As[(wm + i * 16 + qm) * 32 + quad * 8];
#pragma unroll
        for (int j = 0; j < 4; j++) bfr[j] = *(const f16x8*)&Bs[(wn + j * 16 + qm) * 32 + quad * 8];
#pragma unroll
        for (int i = 0; i < 4; i++)
#pragma unroll
            for (int j = 0; j < 4; j++)
                acc[i][j] = __builtin_amdgcn_mfma_f32_16x16x32_f16(af[i], bfr[j], acc[i][j], 0, 0, 0);
        __syncthreads();
    }

#pragma unroll
    for (int i = 0; i < 4; i++) {
#pragma unroll
        for (int j = 0; j < 4; j++) {
            const int col = n0 + wn + j * 16 + qm;
#pragma unroll
            for (int r = 0; r < 4; r++) {
                const int lr = wm + i * 16 + quad * 4 + r;
                const int m = m0 + lr;
                if (m < M) DOWN[(size_t)(base + m) * 1024 + col] = (f16)acc[i][j][r];
            }
        }
    }
}

// ---------------- combine: out[t] = DOWN[16384+t] + DOWN[p1] + DOWN[p2] ----------------
__global__ void combine_kernel(const f16* __restrict__ DOWN, const int* __restrict__ pos,
                               float* __restrict__ OUT) {
    int idx = blockIdx.x * blockDim.x + threadIdx.x;
    int t = idx >> 8;             // 256 threads per token (1024 cols / 4)
    int c = (idx & 255) * 4;
    int p1 = pos[t * 2], p2 = pos[t * 2 + 1];
    f16x4 a = *(const f16x4*)(DOWN + (size_t)(NSLOT + t) * 1024 + c);
    f16x4 b = *(const f16x4*)(DOWN + (size_t)p1 * 1024 + c);
    f16x4 d = *(const f16x4*)(DOWN + (size_t)p2 * 1024 + c);
    float4 o;
    o.x = (float)a[0] + (float)b[0] + (float)d[0];
    o.y = (float)a[1] + (float)b[1] + (float)d[1];
    o.z = (float)a[2] + (float)b[2] + (float)d[2];
    o.w = (float)a[3] + (float)b[3] + (float)d[3];
    *(float4*)(OUT + (size_t)t * 1024 + c) = o;
}

// ---------------- host launch ----------------
extern "C" void kernel_launch(void* const* d_in, const int* in_sizes, int n_in,
                              void* d_out, int out_size, void* d_ws, size_t ws_size,
                              hipStream_t stream) {
    const float* x    = (const float*)d_in[0];   // [8192,1024]
    const float* gw   = (const float*)d_in[1];   // [16,1024]
    const float* wgu  = (const float*)d_in[2];   // [16,1024,1024]
    const float* bgu  = (const float*)d_in[3];   // [16,1024]
    const float* wd   = (const float*)d_in[4];   // [16,1024,512]
    const float* wsgu = (const float*)d_in[5];   // [1024,1024]
    const float* bsgu = (const float*)d_in[6];   // [1024]
    const float* wsd  = (const float*)d_in[7];   // [1024,512]
    float* out = (float*)d_out;

    char* ws = (char*)d_ws;
    size_t off = 0;
    auto take = [&](size_t b) { char* p = ws + off; off = (off + b + 255) & ~(size_t)255; return p; };
    f16* x_h    = (f16*)take((size_t)T_TOK * H_DIM * 2);
    f16* x_l    = (f16*)take((size_t)T_TOK * H_DIM * 2);
    f16* gw_h   = (f16*)take((size_t)N_EXP * H_DIM * 2);
    f16* gw_l   = (f16*)take((size_t)N_EXP * H_DIM * 2);
    f16* wguA   = (f16*)take((size_t)N_ALL * 1024 * H_DIM * 2);   // [17,1024,1024]
    f16* wdA    = (f16*)take((size_t)N_ALL * 1024 * I_DIM * 2);   // [17,1024,512]
    float* biasA = (float*)take((size_t)N_ALL * 1024 * 4);        // [17,1024]
    f16* act    = (f16*)take((size_t)NSLOT_ALL * I_DIM * 2);      // [24576,512]
    f16* down   = (f16*)take((size_t)NSLOT_ALL * 1024 * 2);       // [24576,1024]
    float* logits = (float*)take((size_t)T_TOK * N_EXP * 4);
    int*   sel    = (int*)take((size_t)NSLOT * 4);
    float* rw     = (float*)take((size_t)NSLOT * 4);
    int*   btok   = (int*)take((size_t)NSLOT_ALL * 4);
    float* bw     = (float*)take((size_t)NSLOT_ALL * 4);
    int*   pos    = (int*)take((size_t)NSLOT * 4);
    int*   counts = (int*)take(64);
    int*   offs   = (int*)take(128);
    int*   curs   = (int*)take(64);

    // 1) all casts/splits/copies/zeroing in one launch
    prep_kernel<<<PREP_BLOCKS, 256, 0, stream>>>(x, gw, wgu, wsgu, wd, wsd, bgu, bsgu,
                                                 x_h, x_l, gw_h, gw_l, wguA, wdA, biasA, counts);

    // 2) routing
    logits_kernel<<<T_TOK / 64, 256, 0, stream>>>(x_h, x_l, gw_h, gw_l, logits);
    topk_kernel<<<T_TOK / 256, 256, 0, stream>>>(logits, sel, rw, counts);
    prefix_kernel<<<1, 64, 0, stream>>>(counts, offs, curs);
    scatter_kernel<<<T_TOK / 256, 256, 0, stream>>>(sel, rw, curs, btok, bw, pos);

    // 3) fused gate_up + SiLU*up*bw -> ACT (128 x 64-inter tiles, ny=8)
    gemm_gateup_act<<<dim3(128, 8, N_ALL), 256, 0, stream>>>(x_h, wguA, biasA, bw, act, offs, btok);

    // 4) down GEMM (128x128 tile) -> DOWN
    gemm_down<<<dim3(128, 8, N_ALL), 256, 0, stream>>>(act, wdA, down, offs);

    // 5) combine
    combine_kernel<<<T_TOK * 1024 / 4 / 256, 256, 0, stream>>>(down, pos, out);
}